// Round 9
// baseline (68.715 us; speedup 1.0000x reference)
//
#include <hip/hip_runtime.h>
#include <hip/hip_bf16.h>

typedef __attribute__((ext_vector_type(8))) short bf16x8;
typedef __attribute__((ext_vector_type(4))) float f32x4;

#define CDIM 192
#define NTOK 196
#define LTOT 392
#define BDIM 256
#define NBE 64

__device__ __forceinline__ ushort f2bf(float f) {
  uint u = __float_as_uint(f);
  u = (u + 0x7FFFu + ((u >> 16) & 1u)) >> 16;
  return (ushort)u;
}
__device__ __forceinline__ float bf2f(ushort h) {
  return __uint_as_float(((uint)h) << 16);
}
__device__ __forceinline__ uint pk2(float lo, float hi) {
  __hip_bfloat162 t = __float22bfloat162_rn(float2{lo, hi});
  uint r;
  __builtin_memcpy(&r, &t, 4);
  return r;
}
__device__ __forceinline__ float wave_reduce(float a) {
#pragma unroll
  for (int off = 32; off > 0; off >>= 1) a += __shfl_xor(a, off);
  return a;
}

// ---------------- prep: fold BN (bf16 weights), u3/u4/K via wave-reductions ---
__global__ __launch_bounds__(256) void prep_kernel(
    const float* __restrict__ w1, const float* __restrict__ b1, const float* __restrict__ g1,
    const float* __restrict__ be1, const float* __restrict__ m1, const float* __restrict__ v1,
    const float* __restrict__ w2, const float* __restrict__ b2, const float* __restrict__ g2,
    const float* __restrict__ be2, const float* __restrict__ m2, const float* __restrict__ v2,
    const float* __restrict__ w3, const float* __restrict__ b3,
    const float* __restrict__ w4, const float* __restrict__ b4,
    const float* __restrict__ w5, const float* __restrict__ b5,
    ushort* __restrict__ w1b, ushort* __restrict__ w2b,
    float* __restrict__ u3, float* __restrict__ u4, float* __restrict__ cvecs,
    float* __restrict__ Kc, float* __restrict__ s) {
  const int bid = blockIdx.x;
  const int wid = threadIdx.x >> 6, lane = threadIdx.x & 63;
  if (bid < NBE) {
    for (int i = bid * BDIM + threadIdx.x; i < 123264; i += NBE * BDIM) {
      if (i < 36864) {
        int o = i / CDIM;
        float inv = g1[o] * rsqrtf(v1[o] + 1e-5f);
        w1b[i] = f2bf(w1[i] * inv);
      } else if (i < 73728) {
        int j = i - 36864; int o = j / CDIM;
        float inv = g2[o] * rsqrtf(v2[o] + 1e-5f);
        w2b[j] = f2bf(w2[j] * inv);
      } else if (i < 74112) {
        int k = i - 73728; int h = k / CDIM, o = k % CDIM;
        const float* bb = h ? b2 : b1; const float* gg = h ? g2 : g1;
        const float* bee = h ? be2 : be1;
        const float* mm = h ? m2 : m1; const float* vv = h ? v2 : v1;
        float inv = gg[o] * rsqrtf(vv[o] + 1e-5f);
        cvecs[k] = (bb[o] - mm[o]) * inv + bee[o];
      } else {
        s[i - 74112] = 0.f;
      }
    }
  } else if (bid < NBE + 48) {            // u3: wave per output j
    int j = (bid - NBE) * 4 + wid;
    float a = 0.f;
    for (int c = lane; c < CDIM; c += 64) a += w5[c] * w3[c * CDIM + j];
    a = wave_reduce(a);
    if (lane == 0) u3[j] = a;
  } else if (bid < NBE + 48 + 98) {       // u4: wave per output j
    int j = (bid - NBE - 48) * 4 + wid;
    float a = 0.f;
    for (int o = lane; o < 784; o += 64)
      a += w5[CDIM + o] * (w4[o * 784 + j] + w4[o * 784 + j + LTOT]);
    a = wave_reduce(a);
    if (lane == 0) u4[j] = a;
  } else {                                // Kc: single wave
    if (wid == 0) {
      float a = 0.f;
      for (int i = lane; i < CDIM + 784; i += 64)
        a += (i < CDIM) ? w5[i] * b3[i] : w5[i] * b4[i - CDIM];
      a = wave_reduce(a);
      if (lane == 0) Kc[0] = a + b5[0];
    }
  }
}

// ---------------- phi GEMM v5: coalesced stage -> swizzled LDS -> MFMA --------
// Block = (b,h,g). 2 rounds of 64 rows each; dbuf LDS A-tile; B in regs.
__global__ __launch_bounds__(256) void phi_kernel(
    const float* __restrict__ x, const float* __restrict__ y,
    const ushort* __restrict__ w1b, const ushort* __restrict__ w2b,
    const float* __restrict__ cvecs, const float* __restrict__ u4,
    ushort* __restrict__ phiT, float* __restrict__ s) {
  const int bid = blockIdx.x;             // 1024 = 256 b * 2 h * 2 g
  const int b = bid >> 2, h = (bid >> 1) & 1, g = bid & 1;
  const float* __restrict__ src = (h ? y : x) + (size_t)b * NTOK * CDIM;
  const ushort* __restrict__ wb = h ? w2b : w1b;
  __shared__ ushort Abuf[2][64 * CDIM];   // 2 x 24KB, XOR-swizzled rows
  __shared__ float u4s[208];
  __shared__ float cs[CDIM];
  const int tid = threadIdx.x;
  for (int i = tid; i < 208; i += BDIM) u4s[i] = (i < NTOK) ? u4[h * NTOK + i] : 0.f;
  for (int i = tid; i < CDIM; i += BDIM) cs[i] = cvecs[h * CDIM + i];

  const int wid = tid >> 6, lane = tid & 63;
  const int lrow = lane & 15, kgrp = lane >> 4;
  const int cbase = wid * 48 + lrow;      // wave owns channels [wid*48, wid*48+48)

  bf16x8 bfr[3][6];                       // B-fragments, loaded once per block
#pragma unroll
  for (int ct = 0; ct < 3; ct++)
#pragma unroll
    for (int kk = 0; kk < 6; kk++)
      bfr[ct][kk] = *(const bf16x8*)(wb + (size_t)(cbase + ct * 16) * CDIM + kk * 32 + kgrp * 8);
  __syncthreads();
  const float csr[3] = {cs[cbase], cs[cbase + 16], cs[cbase + 32]};

  const float4* src4 = (const float4*)src;
  const int NF4 = NTOK * CDIM / 4;        // 9408 float4s total
  float sp[3] = {0.f, 0.f, 0.f};

  const int r0 = g * 2, r1 = r0 + 2;
  float4 pf[12];
#pragma unroll
  for (int p = 0; p < 12; p++) {          // prefetch first round of this block
    const int fi = r0 * 3072 + p * 256 + tid;
    pf[p] = (fi < NF4) ? src4[fi] : float4{0.f, 0.f, 0.f, 0.f};
  }

  for (int r = r0; r < r1; r++) {
    ushort* Ab = &Abuf[r & 1][0];
    // convert + swizzled ds_write
#pragma unroll
    for (int p = 0; p < 12; p++) {
      const int fi = r * 3072 + p * 256 + tid;
      const int e = fi * 4;
      const int row = e / CDIM;
      const int col = e - row * CDIM;
      const int rl = row & 63;
      uint2 wv;
      if (fi < NF4) { wv.x = pk2(pf[p].x, pf[p].y); wv.y = pk2(pf[p].z, pf[p].w); }
      else          { wv.x = 0u; wv.y = 0u; }
      uint addr = (uint)(rl * (CDIM * 2) + col * 2);
      addr ^= (uint)((rl & 7) << 4);
      *(uint2*)((char*)Ab + addr) = wv;
    }
    // prefetch next round while this round computes
    if (r + 1 < r1) {
#pragma unroll
      for (int p = 0; p < 12; p++) {
        const int fi = (r + 1) * 3072 + p * 256 + tid;
        pf[p] = (fi < NF4) ? src4[fi] : float4{0.f, 0.f, 0.f, 0.f};
      }
    }
    __syncthreads();
    // compute: 4 row-tiles of 16, each wave does all tiles (48 ch per wave)
#pragma unroll
    for (int tt = 0; tt < 4; tt++) {
      const int l0 = r * 64 + tt * 16;
      if (l0 < NTOK) {
        bf16x8 afr[6];
#pragma unroll
        for (int kk = 0; kk < 6; kk++) {
          uint addr = (uint)((tt * 16 + lrow) * (CDIM * 2) + (kk * 32 + kgrp * 8) * 2);
          addr ^= (uint)((lrow & 7) << 4);
          afr[kk] = *(const bf16x8*)((const char*)Ab + addr);
        }
        f32x4 acc0 = {0.f,0.f,0.f,0.f}, acc1 = {0.f,0.f,0.f,0.f}, acc2 = {0.f,0.f,0.f,0.f};
#pragma unroll
        for (int kk = 0; kk < 6; kk++) {
          acc0 = __builtin_amdgcn_mfma_f32_16x16x32_bf16(afr[kk], bfr[0][kk], acc0, 0, 0, 0);
          acc1 = __builtin_amdgcn_mfma_f32_16x16x32_bf16(afr[kk], bfr[1][kk], acc1, 0, 0, 0);
          acc2 = __builtin_amdgcn_mfma_f32_16x16x32_bf16(afr[kk], bfr[2][kk], acc2, 0, 0, 0);
        }
        const int lbase = l0 + 4 * kgrp;
        const float4 u4v = *(const float4*)&u4s[lbase];
        ushort* pT = phiT + ((size_t)b * LTOT + h * NTOK + lbase) * CDIM + cbase;
        auto epi = [&](const f32x4& acc, int ct, float& spc) {
          const float v0 = fmaxf(acc[0] + csr[ct], 0.f);
          const float v1 = fmaxf(acc[1] + csr[ct], 0.f);
          const float v2 = fmaxf(acc[2] + csr[ct], 0.f);
          const float v3 = fmaxf(acc[3] + csr[ct], 0.f);
          const uint p01 = pk2(v0, v1), p23 = pk2(v2, v3);
          ushort* q = pT + ct * 16;
          if (lbase + 0 < NTOK) q[0 * CDIM] = (ushort)p01;
          if (lbase + 1 < NTOK) q[1 * CDIM] = (ushort)(p01 >> 16);
          if (lbase + 2 < NTOK) q[2 * CDIM] = (ushort)p23;
          if (lbase + 3 < NTOK) q[3 * CDIM] = (ushort)(p23 >> 16);
          spc += u4v.x * v0 + u4v.y * v1 + u4v.z * v2 + u4v.w * v3;
        };
        epi(acc0, 0, sp[0]); epi(acc1, 1, sp[1]); epi(acc2, 2, sp[2]);
      }
    }
  }
#pragma unroll
  for (int ct = 0; ct < 3; ct++) {
    float v = sp[ct];
    v += __shfl_xor(v, 16);
    v += __shfl_xor(v, 32);
    if (kgrp == 0) atomicAdd(&s[b * CDIM + cbase + ct * 16], v);
  }
}

// ------- fused W + out: block = (b, n-tile of 28). 196 = 7*28, no masks. -----
// W[b,l] = sum_c (u3[c]+s[b,c]) phi[b,c,l] + K  for this tile's 56 l's,
// then out[b,c,n] = x[b,n,c]*W[b,n] + y[b,n,c]*W[b,n+196].
__global__ __launch_bounds__(256) void wout_kernel(
    const float* __restrict__ x, const float* __restrict__ y,
    const ushort* __restrict__ phiT, const float* __restrict__ s,
    const float* __restrict__ u3, const float* __restrict__ Kc,
    float* __restrict__ out) {
  const int bid = blockIdx.x;
  const int b = bid / 7, nt = bid % 7;
  const int n0 = nt * 28;
  __shared__ float coeff[CDIM];
  __shared__ float Wl[56];
  __shared__ float tile[28][193];
  const int tid = threadIdx.x;
  for (int i = tid; i < CDIM; i += BDIM) coeff[i] = u3[i] + s[b * CDIM + i];
  __syncthreads();
  // ---- W phase: 4-lane group per row; rows = 28 (h0) + 28 (h1)
  const int wv = tid >> 6, lane = tid & 63;
  const int rloc = wv * 16 + (lane >> 2), g4 = lane & 3;
  if (rloc < 56) {
    const int lg = (rloc < 28) ? (n0 + rloc) : (NTOK + n0 + rloc - 28);
    const ushort* p = phiT + ((size_t)b * LTOT + lg) * CDIM + g4 * 48;
    float acc = 0.f;
#pragma unroll
    for (int q = 0; q < 12; q++) {
      ushort4 v = *(const ushort4*)(p + q * 4);
      const float* cf = &coeff[g4 * 48 + q * 4];
      acc += cf[0] * bf2f(v.x) + cf[1] * bf2f(v.y) +
             cf[2] * bf2f(v.z) + cf[3] * bf2f(v.w);
    }
    acc += __shfl_xor(acc, 1);
    acc += __shfl_xor(acc, 2);
    if (g4 == 0) Wl[rloc] = acc + Kc[0];
  }
  __syncthreads();
  // ---- combine phase: float4 loads, write tile[n][c]
  for (int i = tid; i < 28 * 48; i += BDIM) {
    const int nl = i / 48, c4 = (i % 48) * 4;
    const size_t xi = ((size_t)b * NTOK + n0 + nl) * CDIM + c4;
    const float4 xv = *(const float4*)&x[xi];
    const float4 yv = *(const float4*)&y[xi];
    const float wx = Wl[nl], wy = Wl[28 + nl];
    tile[nl][c4 + 0] = xv.x * wx + yv.x * wy;
    tile[nl][c4 + 1] = xv.y * wx + yv.y * wy;
    tile[nl][c4 + 2] = xv.z * wx + yv.z * wy;
    tile[nl][c4 + 3] = xv.w * wx + yv.w * wy;
  }
  __syncthreads();
  // ---- store phase: float4 along n
  for (int i = tid; i < CDIM * 7; i += BDIM) {
    const int c = i / 7, nq = i % 7;
    float4 o;
    o.x = tile[nq * 4 + 0][c]; o.y = tile[nq * 4 + 1][c];
    o.z = tile[nq * 4 + 2][c]; o.w = tile[nq * 4 + 3][c];
    *(float4*)&out[((size_t)b * CDIM + c) * NTOK + n0 + nq * 4] = o;
  }
}

extern "C" void kernel_launch(void* const* d_in, const int* in_sizes, int n_in,
                              void* d_out, int out_size, void* d_ws, size_t ws_size,
                              hipStream_t stream) {
  const float* x   = (const float*)d_in[0];
  const float* y   = (const float*)d_in[1];
  const float* w1  = (const float*)d_in[2];
  const float* b1  = (const float*)d_in[3];
  const float* g1  = (const float*)d_in[4];
  const float* be1 = (const float*)d_in[5];
  const float* m1  = (const float*)d_in[6];
  const float* v1  = (const float*)d_in[7];
  const float* w2  = (const float*)d_in[8];
  const float* b2  = (const float*)d_in[9];
  const float* g2  = (const float*)d_in[10];
  const float* be2 = (const float*)d_in[11];
  const float* m2  = (const float*)d_in[12];
  const float* v2  = (const float*)d_in[13];
  const float* w3  = (const float*)d_in[14];
  const float* b3  = (const float*)d_in[15];
  const float* w4  = (const float*)d_in[16];
  const float* b4  = (const float*)d_in[17];
  const float* w5  = (const float*)d_in[18];
  const float* b5  = (const float*)d_in[19];
  float* out = (float*)d_out;

  char* ws = (char*)d_ws;
  ushort* w1b  = (ushort*)ws;             // 73728 B
  ushort* w2b  = (ushort*)(ws + 73728);   // 73728 B
  float* fbase = (float*)(ws + 147456);
  float* u3    = fbase;                   // 192
  float* u4    = fbase + 192;             // 392
  float* cvecs = fbase + 584;             // 384 (c1|c2)
  float* Kc    = fbase + 968;             // 1
  float* s     = fbase + 976;             // 256*192 = 49152
  // phiT lives in the workspace (ws >= 256MB per round-7 poison-fill evidence);
  // it must NOT alias d_out because wout_kernel reads phiT while writing out.
  ushort* phiT = (ushort*)(ws + (1 << 22));  // 38.5 MB at +4MB

  prep_kernel<<<211, BDIM, 0, stream>>>(w1, b1, g1, be1, m1, v1,
                                        w2, b2, g2, be2, m2, v2,
                                        w3, b3, w4, b4, w5, b5,
                                        w1b, w2b, u3, u4, cvecs, Kc, s);
  phi_kernel<<<1024, BDIM, 0, stream>>>(x, y, w1b, w2b, cvecs, u4, phiT, s);
  wout_kernel<<<256 * 7, BDIM, 0, stream>>>(x, y, phiT, s, u3, Kc, out);
}

// Round 10
// 62.159 us; speedup vs baseline: 1.1055x; 1.1055x over previous
//
#include <hip/hip_runtime.h>
#include <hip/hip_bf16.h>

typedef __attribute__((ext_vector_type(8))) short bf16x8;
typedef __attribute__((ext_vector_type(4))) float f32x4;

#define CDIM 192
#define NTOK 196
#define LTOT 392
#define BDIM 256
#define NBE 64

__device__ __forceinline__ ushort f2bf(float f) {
  uint u = __float_as_uint(f);
  u = (u + 0x7FFFu + ((u >> 16) & 1u)) >> 16;
  return (ushort)u;
}
__device__ __forceinline__ float bf2f(ushort h) {
  return __uint_as_float(((uint)h) << 16);
}
__device__ __forceinline__ uint pk2(float lo, float hi) {
  __hip_bfloat162 t = __float22bfloat162_rn(float2{lo, hi});
  uint r;
  __builtin_memcpy(&r, &t, 4);
  return r;
}
__device__ __forceinline__ float wave_reduce(float a) {
#pragma unroll
  for (int off = 32; off > 0; off >>= 1) a += __shfl_xor(a, off);
  return a;
}

// ---------------- prep: fold BN (bf16 weights), u3/u4/K via wave-reductions ---
__global__ __launch_bounds__(256) void prep_kernel(
    const float* __restrict__ w1, const float* __restrict__ b1, const float* __restrict__ g1,
    const float* __restrict__ be1, const float* __restrict__ m1, const float* __restrict__ v1,
    const float* __restrict__ w2, const float* __restrict__ b2, const float* __restrict__ g2,
    const float* __restrict__ be2, const float* __restrict__ m2, const float* __restrict__ v2,
    const float* __restrict__ w3, const float* __restrict__ b3,
    const float* __restrict__ w4, const float* __restrict__ b4,
    const float* __restrict__ w5, const float* __restrict__ b5,
    ushort* __restrict__ w1b, ushort* __restrict__ w2b,
    float* __restrict__ u3, float* __restrict__ u4, float* __restrict__ cvecs,
    float* __restrict__ Kc, float* __restrict__ s) {
  const int bid = blockIdx.x;
  const int wid = threadIdx.x >> 6, lane = threadIdx.x & 63;
  if (bid < NBE) {
    for (int i = bid * BDIM + threadIdx.x; i < 123264; i += NBE * BDIM) {
      if (i < 36864) {
        int o = i / CDIM;
        float inv = g1[o] * rsqrtf(v1[o] + 1e-5f);
        w1b[i] = f2bf(w1[i] * inv);
      } else if (i < 73728) {
        int j = i - 36864; int o = j / CDIM;
        float inv = g2[o] * rsqrtf(v2[o] + 1e-5f);
        w2b[j] = f2bf(w2[j] * inv);
      } else if (i < 74112) {
        int k = i - 73728; int h = k / CDIM, o = k % CDIM;
        const float* bb = h ? b2 : b1; const float* gg = h ? g2 : g1;
        const float* bee = h ? be2 : be1;
        const float* mm = h ? m2 : m1; const float* vv = h ? v2 : v1;
        float inv = gg[o] * rsqrtf(vv[o] + 1e-5f);
        cvecs[k] = (bb[o] - mm[o]) * inv + bee[o];
      } else {
        s[i - 74112] = 0.f;
      }
    }
  } else if (bid < NBE + 48) {            // u3: wave per output j
    int j = (bid - NBE) * 4 + wid;
    float a = 0.f;
    for (int c = lane; c < CDIM; c += 64) a += w5[c] * w3[c * CDIM + j];
    a = wave_reduce(a);
    if (lane == 0) u3[j] = a;
  } else if (bid < NBE + 48 + 98) {       // u4: wave per output j
    int j = (bid - NBE - 48) * 4 + wid;
    float a = 0.f;
    for (int o = lane; o < 784; o += 64)
      a += w5[CDIM + o] * (w4[o * 784 + j] + w4[o * 784 + j + LTOT]);
    a = wave_reduce(a);
    if (lane == 0) u4[j] = a;
  } else {                                // Kc: single wave
    if (wid == 0) {
      float a = 0.f;
      for (int i = lane; i < CDIM + 784; i += 64)
        a += (i < CDIM) ? w5[i] * b3[i] : w5[i] * b4[i - CDIM];
      a = wave_reduce(a);
      if (lane == 0) Kc[0] = a + b5[0];
    }
  }
}

// -------- phi GEMM v6: 32-row rounds, LDS out-buffer, coalesced phiT dump -----
// Block = (b,h). 7 rounds; A dbuf 2x12KB + Obuf 12KB; B-frags in regs.
__global__ __launch_bounds__(256) void phi_kernel(
    const float* __restrict__ x, const float* __restrict__ y,
    const ushort* __restrict__ w1b, const ushort* __restrict__ w2b,
    const float* __restrict__ cvecs, const float* __restrict__ u4,
    ushort* __restrict__ phiT, float* __restrict__ s) {
  const int bh = blockIdx.x, b = bh >> 1, h = bh & 1;
  const float* __restrict__ src = (h ? y : x) + (size_t)b * NTOK * CDIM;
  const ushort* __restrict__ wb = h ? w2b : w1b;
  __shared__ ushort Abuf[2][32 * CDIM];   // 2 x 12KB, XOR-swizzled rows
  __shared__ ushort Obuf[32 * CDIM];      // 12KB, XOR-swizzled rows
  __shared__ float u4s[224];
  __shared__ float cs[CDIM];
  const int tid = threadIdx.x;
  for (int i = tid; i < 224; i += BDIM) u4s[i] = (i < NTOK) ? u4[h * NTOK + i] : 0.f;
  for (int i = tid; i < CDIM; i += BDIM) cs[i] = cvecs[h * CDIM + i];

  const int wid = tid >> 6, lane = tid & 63;
  const int lrow = lane & 15, kgrp = lane >> 4;
  const int cbase = wid * 48 + lrow;      // wave owns channels [wid*48, wid*48+48)

  bf16x8 bfr[3][6];                       // B-fragments, loaded once per block
#pragma unroll
  for (int ct = 0; ct < 3; ct++)
#pragma unroll
    for (int kk = 0; kk < 6; kk++)
      bfr[ct][kk] = *(const bf16x8*)(wb + (size_t)(cbase + ct * 16) * CDIM + kk * 32 + kgrp * 8);
  __syncthreads();
  const float csr[3] = {cs[cbase], cs[cbase + 16], cs[cbase + 32]};

  const float4* src4 = (const float4*)src;
  const int NF4 = NTOK * CDIM / 4;        // 9408 float4s total
  float sp[3] = {0.f, 0.f, 0.f};

  float4 pf[6];
#pragma unroll
  for (int p = 0; p < 6; p++) {           // prefetch round 0 (fully valid)
    pf[p] = src4[p * 256 + tid];
  }

  for (int r = 0; r < 7; r++) {           // 7 rounds of 32 rows (196 = 6*32+4)
    ushort* Ab = &Abuf[r & 1][0];
    // stage current round from pf: convert + swizzled ds_write
#pragma unroll
    for (int p = 0; p < 6; p++) {
      const int fi = r * 1536 + p * 256 + tid;
      const int rowg = fi / 48;           // global row (48 float4 per row)
      const int col = (fi - rowg * 48) * 4;
      const int rl = rowg & 31;
      uint2 wv;
      if (fi < NF4) { wv.x = pk2(pf[p].x, pf[p].y); wv.y = pk2(pf[p].z, pf[p].w); }
      else          { wv.x = 0u; wv.y = 0u; }
      uint addr = (uint)(rl * (CDIM * 2) + col * 2);
      addr ^= (uint)((rl & 7) << 4);
      *(uint2*)((char*)Ab + addr) = wv;
    }
    // prefetch next round while this round computes
    if (r < 6) {
#pragma unroll
      for (int p = 0; p < 6; p++) {
        const int fi = (r + 1) * 1536 + p * 256 + tid;
        pf[p] = (fi < NF4) ? src4[fi] : float4{0.f, 0.f, 0.f, 0.f};
      }
    }
    __syncthreads();
    // compute: 2 row-tiles of 16; epilogue -> Obuf (LDS), s-partials
#pragma unroll
    for (int tt = 0; tt < 2; tt++) {
      bf16x8 afr[6];
#pragma unroll
      for (int kk = 0; kk < 6; kk++) {
        uint addr = (uint)((tt * 16 + lrow) * (CDIM * 2) + (kk * 32 + kgrp * 8) * 2);
        addr ^= (uint)((lrow & 7) << 4);
        afr[kk] = *(const bf16x8*)((const char*)Ab + addr);
      }
      f32x4 acc0 = {0.f,0.f,0.f,0.f}, acc1 = {0.f,0.f,0.f,0.f}, acc2 = {0.f,0.f,0.f,0.f};
#pragma unroll
      for (int kk = 0; kk < 6; kk++) {
        acc0 = __builtin_amdgcn_mfma_f32_16x16x32_bf16(afr[kk], bfr[0][kk], acc0, 0, 0, 0);
        acc1 = __builtin_amdgcn_mfma_f32_16x16x32_bf16(afr[kk], bfr[1][kk], acc1, 0, 0, 0);
        acc2 = __builtin_amdgcn_mfma_f32_16x16x32_bf16(afr[kk], bfr[2][kk], acc2, 0, 0, 0);
      }
      const int ll = tt * 16 + 4 * kgrp;  // local row base in [0,32)
      const float4 u4v = *(const float4*)&u4s[r * 32 + ll];
      auto epi = [&](const f32x4& acc, int ct, float& spc) {
        const float v0 = fmaxf(acc[0] + csr[ct], 0.f);
        const float v1 = fmaxf(acc[1] + csr[ct], 0.f);
        const float v2 = fmaxf(acc[2] + csr[ct], 0.f);
        const float v3 = fmaxf(acc[3] + csr[ct], 0.f);
        const uint p01 = pk2(v0, v1), p23 = pk2(v2, v3);
        const int c = cbase + ct * 16;
#pragma unroll
        for (int j = 0; j < 4; j++) {
          const int row = ll + j;
          uint addr = (uint)(row * (CDIM * 2) + c * 2);
          addr ^= (uint)((row & 7) << 4);
          const uint piece = (j == 0) ? (p01 & 0xFFFFu) : (j == 1) ? (p01 >> 16)
                           : (j == 2) ? (p23 & 0xFFFFu) : (p23 >> 16);
          *(ushort*)((char*)Obuf + addr) = (ushort)piece;
        }
        spc += u4v.x * v0 + u4v.y * v1 + u4v.z * v2 + u4v.w * v3;
      };
      epi(acc0, 0, sp[0]); epi(acc1, 1, sp[1]); epi(acc2, 2, sp[2]);
    }
    __syncthreads();
    // dump Obuf -> phiT, fully coalesced 16B/lane; rows valid this round
    const int rows = min(32, NTOK - r * 32);
    const int nel = rows * CDIM;          // ushorts to store
    ushort* dst = phiT + ((size_t)b * LTOT + h * NTOK + r * 32) * CDIM;
    for (int off = tid * 8; off < nel; off += BDIM * 8) {
      const int row = off / CDIM;
      uint addr = (uint)(off * 2) ^ (uint)((row & 7) << 4);
      uint4 v = *(const uint4*)((const char*)Obuf + addr);
      *(uint4*)(dst + off) = v;
    }
    // no extra barrier: next round's Obuf writes are ordered by the next
    // round's post-stage __syncthreads (all dump ds_reads drained there).
  }
#pragma unroll
  for (int ct = 0; ct < 3; ct++) {
    float v = sp[ct];
    v += __shfl_xor(v, 16);
    v += __shfl_xor(v, 32);
    if (kgrp == 0) atomicAdd(&s[b * CDIM + cbase + ct * 16], v);
  }
}

// ------- fused W + out: block = (b, n-tile of 28). 196 = 7*28, no masks. -----
__global__ __launch_bounds__(256) void wout_kernel(
    const float* __restrict__ x, const float* __restrict__ y,
    const ushort* __restrict__ phiT, const float* __restrict__ s,
    const float* __restrict__ u3, const float* __restrict__ Kc,
    float* __restrict__ out) {
  const int bid = blockIdx.x;
  const int b = bid / 7, nt = bid % 7;
  const int n0 = nt * 28;
  __shared__ float coeff[CDIM];
  __shared__ float Wl[56];
  __shared__ float tile[28][193];
  const int tid = threadIdx.x;
  for (int i = tid; i < CDIM; i += BDIM) coeff[i] = u3[i] + s[b * CDIM + i];
  __syncthreads();
  // ---- W phase: 4-lane group per row; rows = 28 (h0) + 28 (h1)
  const int wv = tid >> 6, lane = tid & 63;
  const int rloc = wv * 16 + (lane >> 2), g4 = lane & 3;
  if (rloc < 56) {
    const int lg = (rloc < 28) ? (n0 + rloc) : (NTOK + n0 + rloc - 28);
    const ushort* p = phiT + ((size_t)b * LTOT + lg) * CDIM + g4 * 48;
    float acc = 0.f;
#pragma unroll
    for (int q = 0; q < 12; q++) {
      ushort4 v = *(const ushort4*)(p + q * 4);
      const float* cf = &coeff[g4 * 48 + q * 4];
      acc += cf[0] * bf2f(v.x) + cf[1] * bf2f(v.y) +
             cf[2] * bf2f(v.z) + cf[3] * bf2f(v.w);
    }
    acc += __shfl_xor(acc, 1);
    acc += __shfl_xor(acc, 2);
    if (g4 == 0) Wl[rloc] = acc + Kc[0];
  }
  __syncthreads();
  // ---- combine phase: float4 loads, write tile[n][c]
  for (int i = tid; i < 28 * 48; i += BDIM) {
    const int nl = i / 48, c4 = (i % 48) * 4;
    const size_t xi = ((size_t)b * NTOK + n0 + nl) * CDIM + c4;
    const float4 xv = *(const float4*)&x[xi];
    const float4 yv = *(const float4*)&y[xi];
    const float wx = Wl[nl], wy = Wl[28 + nl];
    tile[nl][c4 + 0] = xv.x * wx + yv.x * wy;
    tile[nl][c4 + 1] = xv.y * wx + yv.y * wy;
    tile[nl][c4 + 2] = xv.z * wx + yv.z * wy;
    tile[nl][c4 + 3] = xv.w * wx + yv.w * wy;
  }
  __syncthreads();
  // ---- store phase: float4 along n
  for (int i = tid; i < CDIM * 7; i += BDIM) {
    const int c = i / 7, nq = i % 7;
    float4 o;
    o.x = tile[nq * 4 + 0][c]; o.y = tile[nq * 4 + 1][c];
    o.z = tile[nq * 4 + 2][c]; o.w = tile[nq * 4 + 3][c];
    *(float4*)&out[((size_t)b * CDIM + c) * NTOK + n0 + nq * 4] = o;
  }
}

extern "C" void kernel_launch(void* const* d_in, const int* in_sizes, int n_in,
                              void* d_out, int out_size, void* d_ws, size_t ws_size,
                              hipStream_t stream) {
  const float* x   = (const float*)d_in[0];
  const float* y   = (const float*)d_in[1];
  const float* w1  = (const float*)d_in[2];
  const float* b1  = (const float*)d_in[3];
  const float* g1  = (const float*)d_in[4];
  const float* be1 = (const float*)d_in[5];
  const float* m1  = (const float*)d_in[6];
  const float* v1  = (const float*)d_in[7];
  const float* w2  = (const float*)d_in[8];
  const float* b2  = (const float*)d_in[9];
  const float* g2  = (const float*)d_in[10];
  const float* be2 = (const float*)d_in[11];
  const float* m2  = (const float*)d_in[12];
  const float* v2  = (const float*)d_in[13];
  const float* w3  = (const float*)d_in[14];
  const float* b3  = (const float*)d_in[15];
  const float* w4  = (const float*)d_in[16];
  const float* b4  = (const float*)d_in[17];
  const float* w5  = (const float*)d_in[18];
  const float* b5  = (const float*)d_in[19];
  float* out = (float*)d_out;

  char* ws = (char*)d_ws;
  ushort* w1b  = (ushort*)ws;             // 73728 B
  ushort* w2b  = (ushort*)(ws + 73728);   // 73728 B
  float* fbase = (float*)(ws + 147456);
  float* u3    = fbase;                   // 192
  float* u4    = fbase + 192;             // 392
  float* cvecs = fbase + 584;             // 384 (c1|c2)
  float* Kc    = fbase + 968;             // 1
  float* s     = fbase + 976;             // 256*192 = 49152
  // phiT lives in the workspace (ws >= 256MB per round-7 poison-fill evidence);
  // it must NOT alias d_out because wout_kernel reads phiT while writing out.
  ushort* phiT = (ushort*)(ws + (1 << 22));  // 38.5 MB at +4MB

  prep_kernel<<<211, BDIM, 0, stream>>>(w1, b1, g1, be1, m1, v1,
                                        w2, b2, g2, be2, m2, v2,
                                        w3, b3, w4, b4, w5, b5,
                                        w1b, w2b, u3, u4, cvecs, Kc, s);
  phi_kernel<<<512, BDIM, 0, stream>>>(x, y, w1b, w2b, cvecs, u4, phiT, s);
  wout_kernel<<<256 * 7, BDIM, 0, stream>>>(x, y, phiT, s, u3, Kc, out);
}